// Round 1
// 561.924 us; speedup vs baseline: 1.0958x; 1.0958x over previous
//
#include <hip/hip_runtime.h>
#include <float.h>
#include <math.h>

// Problem constants (fixed by the reference)
#define NB 1024      // number of graphs B
#define HD 64        // feature dim H
#define NSTEPS 5

__device__ __forceinline__ float sigmoidf_(float x) {
    return 1.0f / (1.0f + __expf(-x));
}

// ---------------- segment boundaries from sorted batch ----------------
__global__ void seg_bounds_kernel(const int* __restrict__ batch,
                                  int* __restrict__ seg_start, int n) {
    int i = blockIdx.x * blockDim.x + threadIdx.x;
    if (i >= n) return;
    int b = batch[i];
    if (i == 0) {
        for (int j = 0; j <= b; ++j) seg_start[j] = 0;
    } else {
        int pb = batch[i - 1];
        for (int j = pb + 1; j <= b; ++j) seg_start[j] = i;
    }
    if (i == n - 1) {
        for (int j = b + 1; j <= NB; ++j) seg_start[j] = n;
    }
}

// async 16B/lane global->LDS. LDS base must be wave-uniform (HW adds lane*16);
// global address is per-lane (clamped tails allowed).
__device__ __forceinline__ void async_ld16(const float* g, float* l) {
    __builtin_amdgcn_global_load_lds(
        (const __attribute__((address_space(1))) void*)g,
        (__attribute__((address_space(3))) void*)l, 16, 0, 0);
}

// One block == one graph. The whole Set2Set recurrence is block-local:
// h, c, r live in LDS; x is streamed via double-buffered global_load_lds
// (4KB tiles per wave, counted vmcnt waits -> deep in-flight queue).
__global__ __launch_bounds__(512, 4) void set2set_fused_kernel(
    const float* __restrict__ x,     // [N,64]
    const int* __restrict__ seg,     // [NB+1]
    const float* __restrict__ W_ih,  // [256,128]
    const float* __restrict__ W_hh,  // [256,64]
    const float* __restrict__ b_ih,  // [256]
    const float* __restrict__ b_hh,  // [256]
    const float* __restrict__ W1,    // [256,128]
    const float* __restrict__ b1,    // [256]
    const float* __restrict__ W2,    // [128,256]
    const float* __restrict__ b2,    // [128]
    float* __restrict__ out)         // [NB,128]
{
    __shared__ __align__(16) float sbuf[8][2][16 * HD];  // 64 KB: 8 waves x dbuf x 16-node tile
    __shared__ __align__(16) float hs[HD], cs[HD], rs[HD];
    __shared__ __align__(16) float gates[256], gpart[256];
    __shared__ __align__(16) float lr[8][HD];
    __shared__ float lm[8], ls[8];

    const int b = blockIdx.x;
    const int tid = threadIdx.x;
    const int lane = tid & 63;
    const int wv = tid >> 6;           // wave 0..7
    const int fc = lane & 15;          // feature chunk (4 floats)
    const int grp = lane >> 4;         // node subgroup 0..3

    const int s0 = seg[b], e0 = seg[b + 1];
    const int len = e0 - s0;
    const int ntiles = (len + 15) >> 4;     // 16-node tiles
    const int maxidx4 = e0 * 16 - 1;        // clamp (global float4 index)

    if (tid < HD) { hs[tid] = 0.0f; cs[tid] = 0.0f; rs[tid] = 0.0f; }
    __syncthreads();

    for (int step = 0; step < NSTEPS; ++step) {
        // ---- prefetch this wave's first tile; overlaps the LSTM below ----
        if (wv < ntiles) {
            const int tb4 = (s0 + wv * 16) * 16;
            float* dst = &sbuf[wv][0][0];
#pragma unroll
            for (int i = 0; i < 4; ++i) {
                int g4 = min(tb4 + i * 64 + lane, maxidx4);
                async_ld16(x + (size_t)g4 * 4, dst + i * 256);
            }
        }

        // ---- LSTM cell (graph-local): gates = W_ih*[h|r] + W_hh*h + biases ----
        if (step == 0) {
            // q_star = h = 0 -> gates are pure bias
            if (tid < 256) gates[tid] = b_ih[tid] + b_hh[tid];
        } else {
            float acc = 0.0f;
            if (tid < 256) {
                acc = b_ih[tid] + b_hh[tid];
                const float4* w = (const float4*)(W_ih + tid * 128);
                const float4* hq = (const float4*)hs;
                const float4* rq = (const float4*)rs;
#pragma unroll
                for (int k = 0; k < 16; ++k) {
                    float4 ww = w[k]; float4 v = hq[k];
                    acc = fmaf(ww.x, v.x, acc); acc = fmaf(ww.y, v.y, acc);
                    acc = fmaf(ww.z, v.z, acc); acc = fmaf(ww.w, v.w, acc);
                }
#pragma unroll
                for (int k = 0; k < 16; ++k) {
                    float4 ww = w[16 + k]; float4 v = rq[k];
                    acc = fmaf(ww.x, v.x, acc); acc = fmaf(ww.y, v.y, acc);
                    acc = fmaf(ww.z, v.z, acc); acc = fmaf(ww.w, v.w, acc);
                }
            } else {
                int j = tid - 256;
                float a2 = 0.0f;
                const float4* w = (const float4*)(W_hh + j * 64);
                const float4* hq = (const float4*)hs;
#pragma unroll
                for (int k = 0; k < 16; ++k) {
                    float4 ww = w[k]; float4 v = hq[k];
                    a2 = fmaf(ww.x, v.x, a2); a2 = fmaf(ww.y, v.y, a2);
                    a2 = fmaf(ww.z, v.z, a2); a2 = fmaf(ww.w, v.w, a2);
                }
                gpart[j] = a2;
            }
            __syncthreads();
            if (tid < 256) gates[tid] = acc + gpart[tid];
        }
        __syncthreads();

        if (tid < HD) {
            float ig = sigmoidf_(gates[tid]);
            float fg = sigmoidf_(gates[tid + 64]);
            float gg = tanhf(gates[tid + 128]);
            float og = sigmoidf_(gates[tid + 192]);
            float cp = (step == 0) ? 0.0f : cs[tid];
            float cn = fmaf(fg, cp, ig * gg);
            cs[tid] = cn;
            hs[tid] = og * tanhf(cn);
        }
        __syncthreads();

        // ---- attention over this graph's nodes, q = h ----
        float4 q4 = *(const float4*)(hs + fc * 4);
        float m = -FLT_MAX, sum = 0.0f;
        float4 r4 = make_float4(0.0f, 0.0f, 0.0f, 0.0f);

        int cur = 0;
        for (int t = wv; t < ntiles; t += 8) {
            // pin: no cross-iteration hoisting of the stage above prior reads
            __builtin_amdgcn_sched_barrier(0);
            int nxt = t + 8;
            if (nxt < ntiles) {
                const int tb4 = (s0 + nxt * 16) * 16;
                float* dst = &sbuf[wv][cur ^ 1][0];
#pragma unroll
                for (int i = 0; i < 4; ++i) {
                    int g4 = min(tb4 + i * 64 + lane, maxidx4);
                    async_ld16(x + (size_t)g4 * 4, dst + i * 256);
                }
                // wait current tile (4 newest outstanding = next tile's DMA)
                asm volatile("s_waitcnt vmcnt(4)" ::: "memory");
            } else {
                asm volatile("s_waitcnt vmcnt(0)" ::: "memory");
            }
            __builtin_amdgcn_sched_barrier(0);

            const float* buf = &sbuf[wv][cur][0];
            const int nbase = t * 16;
#pragma unroll
            for (int u = 0; u < 4; ++u) {
                int nl = u * 4 + grp;
                float4 xv = *(const float4*)(buf + nl * 64 + fc * 4);
                float d = xv.x * q4.x;
                d = fmaf(xv.y, q4.y, d);
                d = fmaf(xv.z, q4.z, d);
                d = fmaf(xv.w, q4.w, d);
                d += __shfl_xor(d, 1);
                d += __shfl_xor(d, 2);
                d += __shfl_xor(d, 4);
                d += __shfl_xor(d, 8);
                bool valid = (nbase + nl) < len;
                float eeff = valid ? d : -FLT_MAX;
                float nm = fmaxf(m, eeff);
                float sc = __expf(m - nm);            // ==1 when m==nm (incl. both -FLT_MAX)
                float w = valid ? __expf(eeff - nm) : 0.0f;
                sum = fmaf(sum, sc, w);
                r4.x = fmaf(r4.x, sc, w * xv.x);
                r4.y = fmaf(r4.y, sc, w * xv.y);
                r4.z = fmaf(r4.z, sc, w * xv.z);
                r4.w = fmaf(r4.w, sc, w * xv.w);
                m = nm;
            }
            cur ^= 1;
        }

        // merge the 4 node-subgroups within the wave
#pragma unroll
        for (int off = 16; off < 64; off <<= 1) {
            float om = __shfl_xor(m, off);
            float os = __shfl_xor(sum, off);
            float ox = __shfl_xor(r4.x, off);
            float oy = __shfl_xor(r4.y, off);
            float oz = __shfl_xor(r4.z, off);
            float ow = __shfl_xor(r4.w, off);
            float nm = fmaxf(m, om);
            float s1 = __expf(m - nm);
            float s2 = __expf(om - nm);
            sum = sum * s1 + os * s2;
            r4.x = r4.x * s1 + ox * s2;
            r4.y = r4.y * s1 + oy * s2;
            r4.z = r4.z * s1 + oz * s2;
            r4.w = r4.w * s1 + ow * s2;
            m = nm;
        }
        if (lane < 16) {
            if (lane == 0) { lm[wv] = m; ls[wv] = sum; }
            *(float4*)&lr[wv][lane * 4] = r4;
        }
        __syncthreads();

        // merge 8 wave partials -> normalized r (stays in LDS)
        if (tid < HD) {
            float M = lm[0];
#pragma unroll
            for (int w = 1; w < 8; ++w) M = fmaxf(M, lm[w]);
            float S = 0.0f, rf = 0.0f;
#pragma unroll
            for (int w = 0; w < 8; ++w) {
                float ww = __expf(lm[w] - M);
                S = fmaf(ls[w], ww, S);
                rf = fmaf(lr[w][tid], ww, rf);
            }
            rs[tid] = rf / fmaxf(S, 1e-16f);
        }
        __syncthreads();
    }

    // ---- MLP head: out = relu([h|r] @ W1^T + b1) @ W2^T + b2 ----
    if (tid < 256) {
        float acc = b1[tid];
        const float4* w = (const float4*)(W1 + tid * 128);
        const float4* hq = (const float4*)hs;
        const float4* rq = (const float4*)rs;
#pragma unroll
        for (int k = 0; k < 16; ++k) {
            float4 ww = w[k]; float4 v = hq[k];
            acc = fmaf(ww.x, v.x, acc); acc = fmaf(ww.y, v.y, acc);
            acc = fmaf(ww.z, v.z, acc); acc = fmaf(ww.w, v.w, acc);
        }
#pragma unroll
        for (int k = 0; k < 16; ++k) {
            float4 ww = w[16 + k]; float4 v = rq[k];
            acc = fmaf(ww.x, v.x, acc); acc = fmaf(ww.y, v.y, acc);
            acc = fmaf(ww.z, v.z, acc); acc = fmaf(ww.w, v.w, acc);
        }
        gates[tid] = fmaxf(acc, 0.0f);   // reuse as hidden activations
    }
    __syncthreads();
    if (tid < 128) {
        float acc = b2[tid];
        const float4* w = (const float4*)(W2 + tid * 256);
        const float4* hq = (const float4*)gates;
#pragma unroll 8
        for (int k = 0; k < 64; ++k) {
            float4 ww = w[k]; float4 v = hq[k];
            acc = fmaf(ww.x, v.x, acc); acc = fmaf(ww.y, v.y, acc);
            acc = fmaf(ww.z, v.z, acc); acc = fmaf(ww.w, v.w, acc);
        }
        out[b * 128 + tid] = acc;
    }
}

extern "C" void kernel_launch(void* const* d_in, const int* in_sizes, int n_in,
                              void* d_out, int out_size, void* d_ws, size_t ws_size,
                              hipStream_t stream) {
    const float* x     = (const float*)d_in[0];   // [N,64]
    const int*   batch = (const int*)d_in[1];     // [N] sorted
    const float* W_ih  = (const float*)d_in[2];   // [256,128]
    const float* W_hh  = (const float*)d_in[3];   // [256,64]
    const float* b_ih  = (const float*)d_in[4];
    const float* b_hh  = (const float*)d_in[5];
    const float* W1    = (const float*)d_in[6];   // [256,128]
    const float* b1    = (const float*)d_in[7];
    const float* W2    = (const float*)d_in[8];   // [128,256]
    const float* b2    = (const float*)d_in[9];
    float* out = (float*)d_out;
    const int N = in_sizes[1];

    int* seg = (int*)d_ws;   // NB+1 ints

    seg_bounds_kernel<<<(N + 255) / 256, 256, 0, stream>>>(batch, seg, N);
    set2set_fused_kernel<<<NB, 512, 0, stream>>>(x, seg, W_ih, W_hh, b_ih, b_hh,
                                                 W1, b1, W2, b2, out);
}